// Round 7
// baseline (770.450 us; speedup 1.0000x reference)
//
#include <hip/hip_runtime.h>
#include <math.h>

typedef __attribute__((ext_vector_type(8))) short bf16x8;  // 8 bf16 = 4 VGPR
typedef __attribute__((ext_vector_type(4))) short bf16x4;  // 8 B
typedef __attribute__((ext_vector_type(4))) float f32x4;   // C/D frag

#define SSCL (0.08838834764831845f * 1.4426950408889634f)  // 1/sqrt(128) * log2(e)

__device__ __forceinline__ short f2bf(float f) {
    union { float f; unsigned u; } x; x.f = f;
    unsigned r = x.u + 0x7fffu + ((x.u >> 16) & 1u);
    return (short)(r >> 16);
}
__device__ __forceinline__ unsigned pack2bf(float a, float b) {
    return ((unsigned)(unsigned short)f2bf(a)) | (((unsigned)(unsigned short)f2bf(b)) << 16);
}

typedef const __attribute__((address_space(1))) unsigned int* gas_ptr;
typedef __attribute__((address_space(3))) unsigned int* las_ptr;
__device__ __forceinline__ void async_copy16(const void* g, void* l) {
    __builtin_amdgcn_global_load_lds((gas_ptr)g, (las_ptr)l, 16, 0, 0);
}

// ---------------------------------------------------------------------------
// fp32 -> bf16 conversion pre-pass (vectorized, grid-stride). n4 = nelem/4.
// ---------------------------------------------------------------------------
__global__ __launch_bounds__(256)
void cvt_kernel(const float* __restrict__ src, short* __restrict__ dst, int n4) {
    int i = blockIdx.x * 256 + threadIdx.x;
    const int stride = gridDim.x * 256;
    for (; i < n4; i += stride) {
        float4 v = ((const float4*)src)[i];
        bf16x4 o;
        o[0] = f2bf(v.x); o[1] = f2bf(v.y); o[2] = f2bf(v.z); o[3] = f2bf(v.w);
        ((bf16x4*)dst)[i] = o;
    }
}

// 3-source variant (weights): blockIdx.y selects src/dst pair.
__global__ __launch_bounds__(256)
void cvt3_kernel(const float* __restrict__ s0, const float* __restrict__ s1,
                 const float* __restrict__ s2, short* __restrict__ d0,
                 short* __restrict__ d1, short* __restrict__ d2, int n4) {
    const float* src = (blockIdx.y == 0) ? s0 : ((blockIdx.y == 1) ? s1 : s2);
    short* dst = (blockIdx.y == 0) ? d0 : ((blockIdx.y == 1) ? d1 : d2);
    int i = blockIdx.x * 256 + threadIdx.x;
    const int stride = gridDim.x * 256;
    for (; i < n4; i += stride) {
        float4 v = ((const float4*)src)[i];
        bf16x4 o;
        o[0] = f2bf(v.x); o[1] = f2bf(v.y); o[2] = f2bf(v.z); o[3] = f2bf(v.w);
        ((bf16x4*)dst)[i] = o;
    }
}

// ---------------------------------------------------------------------------
// NT GEMM (m97 pattern): D[m,n] = sum_k A[m,k]*B[n,k], bf16 in, fp32 acc.
// QKV=1: blockIdx.x in [0,48), sel=bx>>4: sel0 -> D16 (bf16 Q, PRE-SCALED by
//        SSCL so attention skips the per-score multiply),
//        sel1/2 -> Dk/Dv fp32 with kv-append row map m + ((m>>11)+1)*2048.
// QKV=0: blockIdx.x in [0,16), D = Df fp32 plain [4096,2048].
// ---------------------------------------------------------------------------
template<int QKV>
__global__ __launch_bounds__(256)
void gemm_kernel(const short* __restrict__ A,
                 const short* __restrict__ B0, const short* __restrict__ B1,
                 const short* __restrict__ B2,
                 short* __restrict__ D16, float* __restrict__ Dk,
                 float* __restrict__ Dv, float* __restrict__ Df) {
    __shared__ short As[128 * 64];
    __shared__ short Bs[128 * 64];
    const int tid = threadIdx.x, w = tid >> 6, ln = tid & 63;
    const int col = ln & 15, quad = ln >> 4;
    const int sel = QKV ? (blockIdx.x >> 4) : 0;
    const int tn = (blockIdx.x & 15) * 128;
    const int tm = blockIdx.y * 128;
    const short* B = (sel == 0) ? B0 : ((sel == 1) ? B1 : B2);

    const int wm = (w >> 1) * 64, wn = (w & 1) * 64;
    const int srow = ln >> 3, scol = (ln & 7) * 8;

    f32x4 acc[4][4];
    for (int i = 0; i < 4; ++i)
        for (int j = 0; j < 4; ++j)
            for (int e = 0; e < 4; ++e) acc[i][j][e] = 0.f;

    for (int k0 = 0; k0 < 2048; k0 += 64) {
        #pragma unroll
        for (int i = 0; i < 4; ++i) {
            int chunk = i * 4 + w;
            int row = chunk * 8 + srow;
            async_copy16(&A[(tm + row) * 2048 + k0 + scol], &As[chunk * 512]);
            async_copy16(&B[(tn + row) * 2048 + k0 + scol], &Bs[chunk * 512]);
        }
        asm volatile("s_waitcnt vmcnt(0)" ::: "memory");
        __syncthreads();
        #pragma unroll
        for (int kk = 0; kk < 2; ++kk) {
            bf16x8 af[4], bfr[4];
            #pragma unroll
            for (int i = 0; i < 4; ++i)
                af[i] = *(const bf16x8*)&As[(wm + i * 16 + col) * 64 + kk * 32 + quad * 8];
            #pragma unroll
            for (int j = 0; j < 4; ++j)
                bfr[j] = *(const bf16x8*)&Bs[(wn + j * 16 + col) * 64 + kk * 32 + quad * 8];
            __builtin_amdgcn_s_setprio(1);
            #pragma unroll
            for (int i = 0; i < 4; ++i)
                #pragma unroll
                for (int j = 0; j < 4; ++j)
                    acc[i][j] = __builtin_amdgcn_mfma_f32_16x16x32_bf16(af[i], bfr[j], acc[i][j], 0, 0, 0);
            __builtin_amdgcn_s_setprio(0);
        }
        __syncthreads();
    }
    // epilogue: C/D layout col = lane&15, row = quad*4 + reg
    for (int i = 0; i < 4; ++i)
        for (int j = 0; j < 4; ++j)
            for (int r = 0; r < 4; ++r) {
                int m = tm + wm + i * 16 + quad * 4 + r;
                int n = tn + wn + j * 16 + col;
                float v = acc[i][j][r];
                if (QKV) {
                    if (sel == 0) {
                        D16[m * 2048 + n] = f2bf(v * SSCL);
                    } else {
                        int orow = m + ((m >> 11) + 1) * 2048;
                        float* D = (sel == 1) ? Dk : Dv;
                        D[orow * 2048 + n] = v;
                    }
                } else {
                    Df[m * 2048 + n] = v;
                }
            }
}

// ---------------------------------------------------------------------------
// K/V prep + history copy fold. One block per (64-key tile, h, b).
// History tiles (k0 < 2048): read pk/pv DIRECTLY, write the bit-exact fp32
// copy into kall/vall (replacing the 4 hipMemcpyAsync) AND the bf16 swizzled
// ktg/vtg. Chunk tiles (k0 >= 2048): read kall/vall (gemm1-written).
// K: bf16 Ktg [b][h][4096][128], row-swizzled Ktg[key][c ^ ((key&7)<<3)].
// V: bf16 transposed Vtg [b][h][128][4096], key swizzled (kr ^ ((d&7)<<3)).
// ---------------------------------------------------------------------------
__global__ __launch_bounds__(256)
void prep_kv(const float* __restrict__ pk, const float* __restrict__ pv,
             float* __restrict__ Kall, float* __restrict__ Vall,
             short* __restrict__ Ktg, short* __restrict__ Vtg) {
    __shared__ short L[64 * 132];
    const int tid = threadIdx.x;
    const int k0 = blockIdx.x * 64;
    const int h = blockIdx.y, b = blockIdx.z;
    const bool hist = (k0 < 2048);
    const float* Ksrc = hist ? pk   + ((size_t)(b * 2048 + k0) * 16 + h) * 128
                             : Kall + ((size_t)(b * 4096 + k0) * 16 + h) * 128;
    const float* Vsrc = hist ? pv   + ((size_t)(b * 2048 + k0) * 16 + h) * 128
                             : Vall + ((size_t)(b * 4096 + k0) * 16 + h) * 128;
    float* Kdst = Kall + ((size_t)(b * 4096 + k0) * 16 + h) * 128;
    float* Vdst = Vall + ((size_t)(b * 4096 + k0) * 16 + h) * 128;
    short* Ko = Ktg + ((size_t)((b * 16 + h) * 4096) + k0) * 128;
    short* Vo = Vtg + ((size_t)(b * 16 + h) * 128) * 4096;
    // ---- K: direct convert + in-row swizzle (+ fp32 history copy) ----
    #pragma unroll
    for (int i = 0; i < 8; ++i) {
        int idx = i * 256 + tid;
        int kr = idx >> 5, c4 = (idx & 31) * 4;
        float4 v = *(const float4*)&Ksrc[(size_t)kr * 2048 + c4];
        if (hist) *(float4*)&Kdst[(size_t)kr * 2048 + c4] = v;
        bf16x4 o4;
        o4[0] = f2bf(v.x); o4[1] = f2bf(v.y); o4[2] = f2bf(v.z); o4[3] = f2bf(v.w);
        *(bf16x4*)&Ko[(size_t)kr * 128 + (c4 ^ ((kr & 7) << 3))] = o4;
    }
    // ---- V: LDS transpose + swizzle (+ fp32 history copy) ----
    #pragma unroll
    for (int i = 0; i < 8; ++i) {
        int idx = i * 256 + tid;
        int r = idx >> 5, c4 = (idx & 31) * 4;
        float4 v = *(const float4*)&Vsrc[(size_t)r * 2048 + c4];
        if (hist) *(float4*)&Vdst[(size_t)r * 2048 + c4] = v;
        bf16x4 o4;
        o4[0] = f2bf(v.x); o4[1] = f2bf(v.y); o4[2] = f2bf(v.z); o4[3] = f2bf(v.w);
        *(bf16x4*)&L[r * 132 + c4] = o4;
    }
    __syncthreads();
    #pragma unroll
    for (int i = 0; i < 8; ++i) {
        int idx = i * 256 + tid;
        int d = idx >> 4, kc4 = (idx & 15) * 4;
        bf16x4 o4;
        o4[0] = L[(kc4 + 0) * 132 + d];
        o4[1] = L[(kc4 + 1) * 132 + d];
        o4[2] = L[(kc4 + 2) * 132 + d];
        o4[3] = L[(kc4 + 3) * 132 + d];
        *(bf16x4*)&Vo[(size_t)d * 4096 + k0 + (kc4 ^ ((d & 7) << 3))] = o4;
    }
}

// ---------------------------------------------------------------------------
// MFMA flash attention v3: swapped QK^T + register P-exchange PV (no P LDS),
// single-buffered V, 48KB LDS -> 3 blocks/CU.
// grid (bh=32, qtile=32), block 256 = 4 waves; 64 q-rows/block.
// QK^T = mfma(K,Q): lane owns q-row col = ln&15, keys j*16+quad*4+r.
// PV = mfma(V^T_asA, P^T_asB) -> O^T[d][q]: B-frag needs B[col=q][k=key] --
// assembled IN REGISTERS via cross-quad shfl of the packed P chunks
// (lane(col,quad) pulls u[2ks+(quad>>1)] from lanes col+32*(quad&1)(+16)).
// Per tile: issue K(t+1)->Ks[p^1]; QK+softmax+pack+exchange; vmcnt(0)+barrier
// (V(t) and K(t+1) landed); PV from Vs; barrier; issue V(t+1)->Vs.
// ---------------------------------------------------------------------------
__global__ __launch_bounds__(256)
void attn_mfma(const short* __restrict__ Q, const short* __restrict__ Ktg,
               const short* __restrict__ Vtg, short* __restrict__ Ot) {
    __shared__ short Ks[2][64 * 128];
    __shared__ short Vs[128 * 64];
    const int tid = threadIdx.x, w = tid >> 6, ln = tid & 63;
    const int col = ln & 15, quad = ln >> 4;
    const int bh = blockIdx.x;
    const int b = bh >> 4, h = bh & 15;
    const int s0 = blockIdx.y * 64;
    const int xk = (col & 7) << 3;   // fragment-read swizzle term

    // Q fragments (one-time); Q is pre-scaled by SSCL in gemm1's epilogue
    bf16x8 qf[4];
    {
        const int qr = (b * 2048 + s0 + w * 16 + col) * 2048 + h * 128;
        #pragma unroll
        for (int ks = 0; ks < 4; ++ks)
            qf[ks] = *(const bf16x8*)&Q[qr + ks * 32 + quad * 8];
    }
    f32x4 o[8];   // O^T: o[dt][r] = O[q=col][d = dt*16 + quad*4 + r]
    #pragma unroll
    for (int i = 0; i < 8; ++i)
        for (int e = 0; e < 4; ++e) o[i][e] = 0.f;
    float m = -1e30f, l = 0.f;      // per-lane state for qrow = col

    const short* Kb = Ktg + ((size_t)(b * 16 + h) * 4096) * 128;
    const short* Vb = Vtg + ((size_t)(b * 16 + h) * 128) * 4096;

    // per-thread staging bases (hoisted)
    const int kr4 = ln >> 4;               // K: row-in-4 within chunk
    const int kc8 = (ln & 15) * 8;         // K: col offset (8 shorts)
    const int vd = (ln >> 3);              // V: d sub-row within chunk
    const int vkofs = (ln & 7) * 8;        // V: key offset within tile

    const int ntiles = 33 + blockIdx.y;    // (2048 + s0 + 64)/64
    const int qp = 2048 + s0 + w * 16 + col;    // my q position (causal bound)
    const int shsrcA = col + ((quad & 1) << 5); // exchange src lane (quad' = 2*(quad&1))
    const bool qhi = (quad >> 1) != 0;

    // ---- prologue: stage tile 0 ----
    #pragma unroll
    for (int i = 0; i < 4; ++i) {
        int ch = i * 4 + w;
        async_copy16(&Kb[(size_t)(ch * 4 + kr4) * 128 + kc8], &Ks[0][ch * 512]);
        async_copy16(&Vb[(size_t)(ch * 8 + vd) * 4096 + vkofs], &Vs[ch * 512]);
    }
    asm volatile("s_waitcnt vmcnt(0)" ::: "memory");
    __syncthreads();

    for (int t = 0; t < ntiles; ++t) {
        const int p = t & 1;
        const int k0 = t * 64;
        const bool pf = (t + 1 < ntiles);   // block-uniform prefetch guard

        // ---- issue next K tile DMA -> Ks[p^1] ----
        if (pf) {
            const int k0n = k0 + 64;
            #pragma unroll
            for (int i = 0; i < 4; ++i) {
                int ch = i * 4 + w;
                async_copy16(&Kb[(size_t)(k0n + ch * 4 + kr4) * 128 + kc8],
                             &Ks[p ^ 1][ch * 512]);
            }
        }

        // ---- swapped QK^T: S^T[key = j*16+quad*4+r][qrow = col] ----
        f32x4 s4[4];
        #pragma unroll
        for (int j = 0; j < 4; ++j)
            for (int e = 0; e < 4; ++e) s4[j][e] = 0.f;
        #pragma unroll
        for (int ks = 0; ks < 4; ++ks) {
            const int dofs = (ks * 32 + quad * 8) ^ xk;
            bf16x8 kf[4];
            #pragma unroll
            for (int j = 0; j < 4; ++j)
                kf[j] = *(const bf16x8*)&Ks[p][(j * 16 + col) * 128 + dofs];
            __builtin_amdgcn_s_setprio(1);
            #pragma unroll
            for (int j = 0; j < 4; ++j)
                s4[j] = __builtin_amdgcn_mfma_f32_16x16x32_bf16(kf[j], qf[ks], s4[j], 0, 0, 0);
            __builtin_amdgcn_s_setprio(0);
        }

        // ---- lane-local online softmax (base-2 domain; Q pre-scaled) ----
        const bool full = (k0 + 63 <= 2048 + s0 + w * 16);  // wave-uniform
        float pp[4][4];
        if (full) {
            #pragma unroll
            for (int j = 0; j < 4; ++j)
                #pragma unroll
                for (int r = 0; r < 4; ++r) pp[j][r] = s4[j][r];
        } else {
            #pragma unroll
            for (int j = 0; j < 4; ++j) {
                #pragma unroll
                for (int r = 0; r < 4; ++r) {
                    int kp = k0 + j * 16 + quad * 4 + r;
                    pp[j][r] = (kp <= qp) ? s4[j][r] : -1e30f;
                }
            }
        }
        float mx = pp[0][0];
        #pragma unroll
        for (int j = 0; j < 4; ++j)
            #pragma unroll
            for (int r = 0; r < 4; ++r) mx = fmaxf(mx, pp[j][r]);
        mx = fmaxf(mx, __shfl_xor(mx, 16));
        mx = fmaxf(mx, __shfl_xor(mx, 32));

        if (__all(mx <= m)) {
            float rs = 0.f;
            #pragma unroll
            for (int j = 0; j < 4; ++j)
                #pragma unroll
                for (int r = 0; r < 4; ++r) { pp[j][r] = exp2f(pp[j][r] - m); rs += pp[j][r]; }
            rs += __shfl_xor(rs, 16);
            rs += __shfl_xor(rs, 32);
            l += rs;
        } else {
            float mn = fmaxf(m, mx);
            float al = exp2f(m - mn);
            m = mn;
            float rs = 0.f;
            #pragma unroll
            for (int j = 0; j < 4; ++j)
                #pragma unroll
                for (int r = 0; r < 4; ++r) { pp[j][r] = exp2f(pp[j][r] - mn); rs += pp[j][r]; }
            rs += __shfl_xor(rs, 16);
            rs += __shfl_xor(rs, 32);
            l = l * al + rs;
            #pragma unroll
            for (int i = 0; i < 8; ++i)
                #pragma unroll
                for (int r = 0; r < 4; ++r) o[i][r] *= al;   // all regs belong to q=col
        }

        // ---- pack P and cross-quad exchange into PV B-fragments ----
        unsigned u[4][2];
        #pragma unroll
        for (int j = 0; j < 4; ++j) {
            u[j][0] = pack2bf(pp[j][0], pp[j][1]);
            u[j][1] = pack2bf(pp[j][2], pp[j][3]);
        }
        unsigned pe[2][4];
        #pragma unroll
        for (int ks = 0; ks < 2; ++ks) {
            const int j0 = 2 * ks, j1 = 2 * ks + 1;
            unsigned A0 = (unsigned)__shfl((int)u[j0][0], shsrcA);
            unsigned A1 = (unsigned)__shfl((int)u[j0][1], shsrcA);
            unsigned A2 = (unsigned)__shfl((int)u[j1][0], shsrcA);
            unsigned A3 = (unsigned)__shfl((int)u[j1][1], shsrcA);
            unsigned B0 = (unsigned)__shfl((int)u[j0][0], shsrcA + 16);
            unsigned B1 = (unsigned)__shfl((int)u[j0][1], shsrcA + 16);
            unsigned B2 = (unsigned)__shfl((int)u[j1][0], shsrcA + 16);
            unsigned B3 = (unsigned)__shfl((int)u[j1][1], shsrcA + 16);
            pe[ks][0] = qhi ? A2 : A0;
            pe[ks][1] = qhi ? A3 : A1;
            pe[ks][2] = qhi ? B2 : B0;
            pe[ks][3] = qhi ? B3 : B1;
        }

        asm volatile("s_waitcnt vmcnt(0)" ::: "memory");  // V(t) + K(t+1) landed
        __syncthreads();

        // ---- PV: O^T[d][q] += V^T(A) x P^T(B) ----
        union { unsigned u4[4]; bf16x8 v8; } pb0, pb1;
        pb0.u4[0] = pe[0][0]; pb0.u4[1] = pe[0][1]; pb0.u4[2] = pe[0][2]; pb0.u4[3] = pe[0][3];
        pb1.u4[0] = pe[1][0]; pb1.u4[1] = pe[1][1]; pb1.u4[2] = pe[1][2]; pb1.u4[3] = pe[1][3];
        #pragma unroll
        for (int dt = 0; dt < 8; ++dt) {
            int row = dt * 16 + col;
            bf16x8 v0 = *(const bf16x8*)&Vs[row * 64 + ((quad * 8) ^ xk)];
            bf16x8 v1 = *(const bf16x8*)&Vs[row * 64 + ((32 + quad * 8) ^ xk)];
            __builtin_amdgcn_s_setprio(1);
            o[dt] = __builtin_amdgcn_mfma_f32_16x16x32_bf16(v0, pb0.v8, o[dt], 0, 0, 0);
            o[dt] = __builtin_amdgcn_mfma_f32_16x16x32_bf16(v1, pb1.v8, o[dt], 0, 0, 0);
            __builtin_amdgcn_s_setprio(0);
        }
        __syncthreads();   // all waves done reading Vs

        // ---- issue next V tile DMA -> Vs (consumed after next tile's QK) ----
        if (pf) {
            const int k0n = k0 + 64;
            #pragma unroll
            for (int i = 0; i < 4; ++i) {
                int ch = i * 4 + w;
                async_copy16(&Vb[(size_t)(ch * 8 + vd) * 4096 + k0n + vkofs],
                             &Vs[ch * 512]);
            }
        }
    }
    // ---- epilogue: q = col, d = dt*16 + quad*4 + r; b64 stores ----
    const float inv = 1.f / l;
    const size_t ob = (size_t)(b * 2048 + s0 + w * 16 + col) * 2048 + h * 128 + quad * 4;
    #pragma unroll
    for (int dt = 0; dt < 8; ++dt) {
        bf16x4 q4;
        q4[0] = f2bf(o[dt][0] * inv);
        q4[1] = f2bf(o[dt][1] * inv);
        q4[2] = f2bf(o[dt][2] * inv);
        q4[3] = f2bf(o[dt][3] * inv);
        *(bf16x4*)&Ot[ob + dt * 16] = q4;
    }
}

// ---------------------------------------------------------------------------
extern "C" void kernel_launch(void* const* d_in, const int* in_sizes, int n_in,
                              void* d_out, int out_size, void* d_ws, size_t ws_size,
                              hipStream_t stream) {
    const float* x  = (const float*)d_in[0];
    const float* pk = (const float*)d_in[1];
    const float* pv = (const float*)d_in[2];
    // d_in[3] = mask (unused: causal structure reproduced analytically)
    const float* wq = (const float*)d_in[4];
    const float* wk = (const float*)d_in[5];
    const float* wv = (const float*)d_in[6];
    const float* wo = (const float*)d_in[7];

    float* out  = (float*)d_out;                 // [2][2048][2048]
    float* kall = out + 8388608;                 // [2][4096][16][128]
    float* vall = out + 25165824;                // [2][4096][16][128]

    short* ws16 = (short*)d_ws;
    // 64 MiB workspace layout (overlapped lifetimes):
    short* xb  = ws16;                // [4096][2048] bf16; dead after gemm1 -> ot
    short* wqb = ws16 + 8388608;      // weights bf16; dead after gemm1
    short* wkb = ws16 + 12582912;
    short* wvb = ws16 + 16777216;
    short* wob = ws16 + 20971520;     // converted AFTER attn (region aliases Vtg)
    short* vtg = ws16 + 8388608;      // [2][16][128][4096] bf16; overlays weights
    short* qbf = ws16 + 25165824;     // [4096][2048] bf16
    short* ot  = xb;                  // alias: xb dead after gemm1
    short* ktg = (short*)out;         // [2][16][4096][128] bf16 = 32 MiB scratch
                                      // in out[0..8388608) floats; dead before
                                      // gemm0 overwrites that region.

    // fp32 -> bf16 pre-pass for x and the QKV weights (wo converted later)
    cvt_kernel<<<1024, 256, 0, stream>>>(x, xb, 2097152);
    cvt3_kernel<<<dim3(512, 3), 256, 0, stream>>>(wq, wk, wv, wqb, wkb, wvb, 1048576);

    // fused QKV projection: Q -> qbf (bf16, pre-scaled), K/V -> kall/vall fp32
    gemm_kernel<1><<<dim3(48, 32), 256, 0, stream>>>(xb, wqb, wkb, wvb,
                                                     qbf, kall, vall, nullptr);
    // K/V prep: history fp32 copy (replaces memcpys) + bf16 swizzled ktg/vtg
    prep_kv<<<dim3(64, 16, 2), 256, 0, stream>>>(pk, pv, kall, vall, ktg, vtg);
    // MFMA flash attention (bh on x for XCD L2 locality; 48KB LDS, 3 blk/CU)
    attn_mfma<<<dim3(32, 32), 256, 0, stream>>>(qbf, ktg, vtg, ot);
    // wo conversion (vtg now dead) + output projection -> out (fp32)
    cvt_kernel<<<512, 256, 0, stream>>>(wo, wob, 1048576);
    gemm_kernel<0><<<dim3(16, 32), 256, 0, stream>>>(ot, wob, wob, wob,
                                                     nullptr, nullptr, nullptr, out);
}

// Round 8
// 769.107 us; speedup vs baseline: 1.0017x; 1.0017x over previous
//
#include <hip/hip_runtime.h>
#include <math.h>

typedef __attribute__((ext_vector_type(8))) short bf16x8;  // 8 bf16 = 4 VGPR
typedef __attribute__((ext_vector_type(4))) short bf16x4;  // 8 B
typedef __attribute__((ext_vector_type(4))) float f32x4;   // C/D frag

#define SSCL (0.08838834764831845f * 1.4426950408889634f)  // 1/sqrt(128) * log2(e)

__device__ __forceinline__ short f2bf(float f) {
    union { float f; unsigned u; } x; x.f = f;
    unsigned r = x.u + 0x7fffu + ((x.u >> 16) & 1u);
    return (short)(r >> 16);
}
__device__ __forceinline__ unsigned pack2bf(float a, float b) {
    return ((unsigned)(unsigned short)f2bf(a)) | (((unsigned)(unsigned short)f2bf(b)) << 16);
}

typedef const __attribute__((address_space(1))) unsigned int* gas_ptr;
typedef __attribute__((address_space(3))) unsigned int* las_ptr;
__device__ __forceinline__ void async_copy16(const void* g, void* l) {
    __builtin_amdgcn_global_load_lds((gas_ptr)g, (las_ptr)l, 16, 0, 0);
}

// ---------------------------------------------------------------------------
// fp32 -> bf16 conversion pre-pass (vectorized, grid-stride). n4 = nelem/4.
// ---------------------------------------------------------------------------
__global__ __launch_bounds__(256)
void cvt_kernel(const float* __restrict__ src, short* __restrict__ dst, int n4) {
    int i = blockIdx.x * 256 + threadIdx.x;
    const int stride = gridDim.x * 256;
    for (; i < n4; i += stride) {
        float4 v = ((const float4*)src)[i];
        bf16x4 o;
        o[0] = f2bf(v.x); o[1] = f2bf(v.y); o[2] = f2bf(v.z); o[3] = f2bf(v.w);
        ((bf16x4*)dst)[i] = o;
    }
}

// 4-source variant: y=0 -> x (n4x), y=1..3 -> weights (n4w each).
__global__ __launch_bounds__(256)
void cvt4_kernel(const float* __restrict__ s0, const float* __restrict__ s1,
                 const float* __restrict__ s2, const float* __restrict__ s3,
                 short* __restrict__ d0, short* __restrict__ d1,
                 short* __restrict__ d2, short* __restrict__ d3,
                 int n4x, int n4w) {
    const int y = blockIdx.y;
    const float* src = (y == 0) ? s0 : ((y == 1) ? s1 : ((y == 2) ? s2 : s3));
    short* dst = (y == 0) ? d0 : ((y == 1) ? d1 : ((y == 2) ? d2 : d3));
    const int n4 = (y == 0) ? n4x : n4w;
    int i = blockIdx.x * 256 + threadIdx.x;
    const int stride = gridDim.x * 256;
    for (; i < n4; i += stride) {
        float4 v = ((const float4*)src)[i];
        bf16x4 o;
        o[0] = f2bf(v.x); o[1] = f2bf(v.y); o[2] = f2bf(v.z); o[3] = f2bf(v.w);
        ((bf16x4*)dst)[i] = o;
    }
}

// ---------------------------------------------------------------------------
// NT GEMM (m97 pattern): D[m,n] = sum_k A[m,k]*B[n,k], bf16 in, fp32 acc.
// QKV=1: blockIdx.x in [0,48), sel=bx>>4: sel0 -> D16 (bf16 Q, PRE-SCALED by
//        SSCL so attention skips the per-score multiply),
//        sel1/2 -> Dk/Dv fp32 with kv-append row map m + ((m>>11)+1)*2048.
// QKV=0: blockIdx.x in [0,16), D = Df fp32 plain [4096,2048].
// ---------------------------------------------------------------------------
template<int QKV>
__global__ __launch_bounds__(256)
void gemm_kernel(const short* __restrict__ A,
                 const short* __restrict__ B0, const short* __restrict__ B1,
                 const short* __restrict__ B2,
                 short* __restrict__ D16, float* __restrict__ Dk,
                 float* __restrict__ Dv, float* __restrict__ Df) {
    __shared__ short As[128 * 64];
    __shared__ short Bs[128 * 64];
    const int tid = threadIdx.x, w = tid >> 6, ln = tid & 63;
    const int col = ln & 15, quad = ln >> 4;
    const int sel = QKV ? (blockIdx.x >> 4) : 0;
    const int tn = (blockIdx.x & 15) * 128;
    const int tm = blockIdx.y * 128;
    const short* B = (sel == 0) ? B0 : ((sel == 1) ? B1 : B2);

    const int wm = (w >> 1) * 64, wn = (w & 1) * 64;
    const int srow = ln >> 3, scol = (ln & 7) * 8;

    f32x4 acc[4][4];
    for (int i = 0; i < 4; ++i)
        for (int j = 0; j < 4; ++j)
            for (int e = 0; e < 4; ++e) acc[i][j][e] = 0.f;

    for (int k0 = 0; k0 < 2048; k0 += 64) {
        #pragma unroll
        for (int i = 0; i < 4; ++i) {
            int chunk = i * 4 + w;
            int row = chunk * 8 + srow;
            async_copy16(&A[(tm + row) * 2048 + k0 + scol], &As[chunk * 512]);
            async_copy16(&B[(tn + row) * 2048 + k0 + scol], &Bs[chunk * 512]);
        }
        asm volatile("s_waitcnt vmcnt(0)" ::: "memory");
        __syncthreads();
        #pragma unroll
        for (int kk = 0; kk < 2; ++kk) {
            bf16x8 af[4], bfr[4];
            #pragma unroll
            for (int i = 0; i < 4; ++i)
                af[i] = *(const bf16x8*)&As[(wm + i * 16 + col) * 64 + kk * 32 + quad * 8];
            #pragma unroll
            for (int j = 0; j < 4; ++j)
                bfr[j] = *(const bf16x8*)&Bs[(wn + j * 16 + col) * 64 + kk * 32 + quad * 8];
            __builtin_amdgcn_s_setprio(1);
            #pragma unroll
            for (int i = 0; i < 4; ++i)
                #pragma unroll
                for (int j = 0; j < 4; ++j)
                    acc[i][j] = __builtin_amdgcn_mfma_f32_16x16x32_bf16(af[i], bfr[j], acc[i][j], 0, 0, 0);
            __builtin_amdgcn_s_setprio(0);
        }
        __syncthreads();
    }
    // epilogue: C/D layout col = lane&15, row = quad*4 + reg
    for (int i = 0; i < 4; ++i)
        for (int j = 0; j < 4; ++j)
            for (int r = 0; r < 4; ++r) {
                int m = tm + wm + i * 16 + quad * 4 + r;
                int n = tn + wn + j * 16 + col;
                float v = acc[i][j][r];
                if (QKV) {
                    if (sel == 0) {
                        D16[m * 2048 + n] = f2bf(v * SSCL);
                    } else {
                        int orow = m + ((m >> 11) + 1) * 2048;
                        float* D = (sel == 1) ? Dk : Dv;
                        D[orow * 2048 + n] = v;
                    }
                } else {
                    Df[m * 2048 + n] = v;
                }
            }
}

// ---------------------------------------------------------------------------
// K/V prep + history copy fold. One block per (64-key tile, h, b).
// History tiles (k0 < 2048): read pk/pv DIRECTLY, write the bit-exact fp32
// copy into kall/vall (replacing the 4 hipMemcpyAsync) AND the bf16 swizzled
// ktg/vtg. Chunk tiles (k0 >= 2048): read kall/vall (gemm1-written).
// K: bf16 Ktg [b][h][4096][128], row-swizzled Ktg[key][c ^ ((key&7)<<3)].
// V: bf16 transposed Vtg [b][h][128][4096], key swizzled (kr ^ ((d&7)<<3)).
// ---------------------------------------------------------------------------
__global__ __launch_bounds__(256)
void prep_kv(const float* __restrict__ pk, const float* __restrict__ pv,
             float* __restrict__ Kall, float* __restrict__ Vall,
             short* __restrict__ Ktg, short* __restrict__ Vtg) {
    __shared__ short L[64 * 132];
    const int tid = threadIdx.x;
    const int k0 = blockIdx.x * 64;
    const int h = blockIdx.y, b = blockIdx.z;
    const bool hist = (k0 < 2048);
    const float* Ksrc = hist ? pk   + ((size_t)(b * 2048 + k0) * 16 + h) * 128
                             : Kall + ((size_t)(b * 4096 + k0) * 16 + h) * 128;
    const float* Vsrc = hist ? pv   + ((size_t)(b * 2048 + k0) * 16 + h) * 128
                             : Vall + ((size_t)(b * 4096 + k0) * 16 + h) * 128;
    float* Kdst = Kall + ((size_t)(b * 4096 + k0) * 16 + h) * 128;
    float* Vdst = Vall + ((size_t)(b * 4096 + k0) * 16 + h) * 128;
    short* Ko = Ktg + ((size_t)((b * 16 + h) * 4096) + k0) * 128;
    short* Vo = Vtg + ((size_t)(b * 16 + h) * 128) * 4096;
    // ---- K: direct convert + in-row swizzle (+ fp32 history copy) ----
    #pragma unroll
    for (int i = 0; i < 8; ++i) {
        int idx = i * 256 + tid;
        int kr = idx >> 5, c4 = (idx & 31) * 4;
        float4 v = *(const float4*)&Ksrc[(size_t)kr * 2048 + c4];
        if (hist) *(float4*)&Kdst[(size_t)kr * 2048 + c4] = v;
        bf16x4 o4;
        o4[0] = f2bf(v.x); o4[1] = f2bf(v.y); o4[2] = f2bf(v.z); o4[3] = f2bf(v.w);
        *(bf16x4*)&Ko[(size_t)kr * 128 + (c4 ^ ((kr & 7) << 3))] = o4;
    }
    // ---- V: LDS transpose + swizzle (+ fp32 history copy) ----
    #pragma unroll
    for (int i = 0; i < 8; ++i) {
        int idx = i * 256 + tid;
        int r = idx >> 5, c4 = (idx & 31) * 4;
        float4 v = *(const float4*)&Vsrc[(size_t)r * 2048 + c4];
        if (hist) *(float4*)&Vdst[(size_t)r * 2048 + c4] = v;
        bf16x4 o4;
        o4[0] = f2bf(v.x); o4[1] = f2bf(v.y); o4[2] = f2bf(v.z); o4[3] = f2bf(v.w);
        *(bf16x4*)&L[r * 132 + c4] = o4;
    }
    __syncthreads();
    #pragma unroll
    for (int i = 0; i < 8; ++i) {
        int idx = i * 256 + tid;
        int d = idx >> 4, kc4 = (idx & 15) * 4;
        bf16x4 o4;
        o4[0] = L[(kc4 + 0) * 132 + d];
        o4[1] = L[(kc4 + 1) * 132 + d];
        o4[2] = L[(kc4 + 2) * 132 + d];
        o4[3] = L[(kc4 + 3) * 132 + d];
        *(bf16x4*)&Vo[(size_t)d * 4096 + k0 + (kc4 ^ ((d & 7) << 3))] = o4;
    }
}

// ---------------------------------------------------------------------------
// MFMA flash attention v4: round-6's 1-barrier double-buffered skeleton +
// round-7's register P-exchange (no P LDS). LDS = Ks[2]+Vs[2] = 64KB.
// grid (bh=32, qtile=32), block 256 = 4 waves; 64 q-rows/block.
// QK^T = mfma(K,Q): lane owns q-row col = ln&15, keys j*16+quad*4+r.
// PV = mfma(V^T_asA, P^T_asB) -> O^T[d][q]: B-frag assembled in registers
// via cross-quad shfl of packed P chunks.
// Per tile t: issue K,V(t+1) -> bufs p^1; QK+softmax+pack+exchange; PV from
// bufs p; ONE vmcnt(0)+barrier.
// ---------------------------------------------------------------------------
__global__ __launch_bounds__(256)
void attn_mfma(const short* __restrict__ Q, const short* __restrict__ Ktg,
               const short* __restrict__ Vtg, short* __restrict__ Ot) {
    __shared__ short Ks[2][64 * 128];
    __shared__ short Vs[2][128 * 64];
    const int tid = threadIdx.x, w = tid >> 6, ln = tid & 63;
    const int col = ln & 15, quad = ln >> 4;
    const int bh = blockIdx.x;
    const int b = bh >> 4, h = bh & 15;
    const int s0 = blockIdx.y * 64;
    const int xk = (col & 7) << 3;   // fragment-read swizzle term

    // Q fragments (one-time); Q is pre-scaled by SSCL in gemm1's epilogue
    bf16x8 qf[4];
    {
        const int qr = (b * 2048 + s0 + w * 16 + col) * 2048 + h * 128;
        #pragma unroll
        for (int ks = 0; ks < 4; ++ks)
            qf[ks] = *(const bf16x8*)&Q[qr + ks * 32 + quad * 8];
    }
    f32x4 o[8];   // O^T: o[dt][r] = O[q=col][d = dt*16 + quad*4 + r]
    #pragma unroll
    for (int i = 0; i < 8; ++i)
        for (int e = 0; e < 4; ++e) o[i][e] = 0.f;
    float m = -1e30f, l = 0.f;      // per-lane state for qrow = col

    const short* Kb = Ktg + ((size_t)(b * 16 + h) * 4096) * 128;
    const short* Vb = Vtg + ((size_t)(b * 16 + h) * 128) * 4096;

    // per-thread staging bases (hoisted)
    const int kr4 = ln >> 4;               // K: row-in-4 within chunk
    const int kc8 = (ln & 15) * 8;         // K: col offset (8 shorts)
    const int vd = (ln >> 3);              // V: d sub-row within chunk
    const int vkofs = (ln & 7) * 8;        // V: key offset within tile

    const int ntiles = 33 + blockIdx.y;    // (2048 + s0 + 64)/64
    const int qp = 2048 + s0 + w * 16 + col;    // my q position (causal bound)
    const int shsrcA = col + ((quad & 1) << 5); // exchange src lane
    const bool qhi = (quad >> 1) != 0;

    // ---- prologue: stage tile 0 into buffers 0 ----
    #pragma unroll
    for (int i = 0; i < 4; ++i) {
        int ch = i * 4 + w;
        async_copy16(&Kb[(size_t)(ch * 4 + kr4) * 128 + kc8], &Ks[0][ch * 512]);
        async_copy16(&Vb[(size_t)(ch * 8 + vd) * 4096 + vkofs], &Vs[0][ch * 512]);
    }
    asm volatile("s_waitcnt vmcnt(0)" ::: "memory");
    __syncthreads();

    for (int t = 0; t < ntiles; ++t) {
        const int p = t & 1;
        const int k0 = t * 64;
        const bool pf = (t + 1 < ntiles);   // block-uniform prefetch guard

        // ---- issue next-tile DMA (K,V -> bufs p^1) ----
        if (pf) {
            const int k0n = k0 + 64;
            #pragma unroll
            for (int i = 0; i < 4; ++i) {
                int ch = i * 4 + w;
                async_copy16(&Kb[(size_t)(k0n + ch * 4 + kr4) * 128 + kc8],
                             &Ks[p ^ 1][ch * 512]);
                async_copy16(&Vb[(size_t)(ch * 8 + vd) * 4096 + k0n + vkofs],
                             &Vs[p ^ 1][ch * 512]);
            }
        }

        // ---- swapped QK^T: S^T[key = j*16+quad*4+r][qrow = col] ----
        f32x4 s4[4];
        #pragma unroll
        for (int j = 0; j < 4; ++j)
            for (int e = 0; e < 4; ++e) s4[j][e] = 0.f;
        #pragma unroll
        for (int ks = 0; ks < 4; ++ks) {
            const int dofs = (ks * 32 + quad * 8) ^ xk;
            bf16x8 kf[4];
            #pragma unroll
            for (int j = 0; j < 4; ++j)
                kf[j] = *(const bf16x8*)&Ks[p][(j * 16 + col) * 128 + dofs];
            __builtin_amdgcn_s_setprio(1);
            #pragma unroll
            for (int j = 0; j < 4; ++j)
                s4[j] = __builtin_amdgcn_mfma_f32_16x16x32_bf16(kf[j], qf[ks], s4[j], 0, 0, 0);
            __builtin_amdgcn_s_setprio(0);
        }

        // ---- lane-local online softmax (base-2 domain; Q pre-scaled) ----
        const bool full = (k0 + 63 <= 2048 + s0 + w * 16);  // wave-uniform
        float pp[4][4];
        if (full) {
            #pragma unroll
            for (int j = 0; j < 4; ++j)
                #pragma unroll
                for (int r = 0; r < 4; ++r) pp[j][r] = s4[j][r];
        } else {
            #pragma unroll
            for (int j = 0; j < 4; ++j) {
                #pragma unroll
                for (int r = 0; r < 4; ++r) {
                    int kp = k0 + j * 16 + quad * 4 + r;
                    pp[j][r] = (kp <= qp) ? s4[j][r] : -1e30f;
                }
            }
        }
        float mx = pp[0][0];
        #pragma unroll
        for (int j = 0; j < 4; ++j)
            #pragma unroll
            for (int r = 0; r < 4; ++r) mx = fmaxf(mx, pp[j][r]);
        mx = fmaxf(mx, __shfl_xor(mx, 16));
        mx = fmaxf(mx, __shfl_xor(mx, 32));

        if (__all(mx <= m)) {
            float rs = 0.f;
            #pragma unroll
            for (int j = 0; j < 4; ++j)
                #pragma unroll
                for (int r = 0; r < 4; ++r) { pp[j][r] = exp2f(pp[j][r] - m); rs += pp[j][r]; }
            rs += __shfl_xor(rs, 16);
            rs += __shfl_xor(rs, 32);
            l += rs;
        } else {
            float mn = fmaxf(m, mx);
            float al = exp2f(m - mn);
            m = mn;
            float rs = 0.f;
            #pragma unroll
            for (int j = 0; j < 4; ++j)
                #pragma unroll
                for (int r = 0; r < 4; ++r) { pp[j][r] = exp2f(pp[j][r] - mn); rs += pp[j][r]; }
            rs += __shfl_xor(rs, 16);
            rs += __shfl_xor(rs, 32);
            l = l * al + rs;
            #pragma unroll
            for (int i = 0; i < 8; ++i)
                #pragma unroll
                for (int r = 0; r < 4; ++r) o[i][r] *= al;   // all regs belong to q=col
        }

        // ---- pack P and cross-quad exchange into PV B-fragments ----
        unsigned u[4][2];
        #pragma unroll
        for (int j = 0; j < 4; ++j) {
            u[j][0] = pack2bf(pp[j][0], pp[j][1]);
            u[j][1] = pack2bf(pp[j][2], pp[j][3]);
        }
        unsigned pe[2][4];
        #pragma unroll
        for (int ks = 0; ks < 2; ++ks) {
            const int j0 = 2 * ks, j1 = 2 * ks + 1;
            unsigned A0 = (unsigned)__shfl((int)u[j0][0], shsrcA);
            unsigned A1 = (unsigned)__shfl((int)u[j0][1], shsrcA);
            unsigned A2 = (unsigned)__shfl((int)u[j1][0], shsrcA);
            unsigned A3 = (unsigned)__shfl((int)u[j1][1], shsrcA);
            unsigned B0 = (unsigned)__shfl((int)u[j0][0], shsrcA + 16);
            unsigned B1 = (unsigned)__shfl((int)u[j0][1], shsrcA + 16);
            unsigned B2 = (unsigned)__shfl((int)u[j1][0], shsrcA + 16);
            unsigned B3 = (unsigned)__shfl((int)u[j1][1], shsrcA + 16);
            pe[ks][0] = qhi ? A2 : A0;
            pe[ks][1] = qhi ? A3 : A1;
            pe[ks][2] = qhi ? B2 : B0;
            pe[ks][3] = qhi ? B3 : B1;
        }

        // ---- PV: O^T[d][q] += V^T(A) x P^T(B), reads Vs[p] ----
        union { unsigned u4[4]; bf16x8 v8; } pb0, pb1;
        pb0.u4[0] = pe[0][0]; pb0.u4[1] = pe[0][1]; pb0.u4[2] = pe[0][2]; pb0.u4[3] = pe[0][3];
        pb1.u4[0] = pe[1][0]; pb1.u4[1] = pe[1][1]; pb1.u4[2] = pe[1][2]; pb1.u4[3] = pe[1][3];
        #pragma unroll
        for (int dt = 0; dt < 8; ++dt) {
            int row = dt * 16 + col;
            bf16x8 v0 = *(const bf16x8*)&Vs[p][row * 64 + ((quad * 8) ^ xk)];
            bf16x8 v1 = *(const bf16x8*)&Vs[p][row * 64 + ((32 + quad * 8) ^ xk)];
            __builtin_amdgcn_s_setprio(1);
            o[dt] = __builtin_amdgcn_mfma_f32_16x16x32_bf16(v0, pb0.v8, o[dt], 0, 0, 0);
            o[dt] = __builtin_amdgcn_mfma_f32_16x16x32_bf16(v1, pb1.v8, o[dt], 0, 0, 0);
            __builtin_amdgcn_s_setprio(0);
        }

        asm volatile("s_waitcnt vmcnt(0)" ::: "memory");  // t+1 DMA landed
        __syncthreads();   // all waves done with bufs p; p^1 ready
    }
    // ---- epilogue: q = col, d = dt*16 + quad*4 + r; b64 stores ----
    const float inv = 1.f / l;
    const size_t ob = (size_t)(b * 2048 + s0 + w * 16 + col) * 2048 + h * 128 + quad * 4;
    #pragma unroll
    for (int dt = 0; dt < 8; ++dt) {
        bf16x4 q4;
        q4[0] = f2bf(o[dt][0] * inv);
        q4[1] = f2bf(o[dt][1] * inv);
        q4[2] = f2bf(o[dt][2] * inv);
        q4[3] = f2bf(o[dt][3] * inv);
        *(bf16x4*)&Ot[ob + dt * 16] = q4;
    }
}

// ---------------------------------------------------------------------------
extern "C" void kernel_launch(void* const* d_in, const int* in_sizes, int n_in,
                              void* d_out, int out_size, void* d_ws, size_t ws_size,
                              hipStream_t stream) {
    const float* x  = (const float*)d_in[0];
    const float* pk = (const float*)d_in[1];
    const float* pv = (const float*)d_in[2];
    // d_in[3] = mask (unused: causal structure reproduced analytically)
    const float* wq = (const float*)d_in[4];
    const float* wk = (const float*)d_in[5];
    const float* wv = (const float*)d_in[6];
    const float* wo = (const float*)d_in[7];

    float* out  = (float*)d_out;                 // [2][2048][2048]
    float* kall = out + 8388608;                 // [2][4096][16][128]
    float* vall = out + 25165824;                // [2][4096][16][128]

    short* ws16 = (short*)d_ws;
    // 64 MiB workspace layout (overlapped lifetimes):
    short* xb  = ws16;                // [4096][2048] bf16; dead after gemm1 -> ot
    short* wqb = ws16 + 8388608;      // weights bf16; dead after gemm1
    short* wkb = ws16 + 12582912;
    short* wvb = ws16 + 16777216;
    short* wob = ws16 + 20971520;     // converted AFTER attn (region aliases Vtg)
    short* vtg = ws16 + 8388608;      // [2][16][128][4096] bf16; overlays weights
    short* qbf = ws16 + 25165824;     // [4096][2048] bf16
    short* ot  = xb;                  // alias: xb dead after gemm1
    short* ktg = (short*)out;         // [2][16][4096][128] bf16 = 32 MiB scratch
                                      // in out[0..8388608) floats; dead before
                                      // gemm0 overwrites that region.

    // fp32 -> bf16 pre-pass: x + the 3 QKV weights in one launch (wo later)
    cvt4_kernel<<<dim3(512, 4), 256, 0, stream>>>(x, wq, wk, wv,
                                                  xb, wqb, wkb, wvb,
                                                  2097152, 1048576);

    // fused QKV projection: Q -> qbf (bf16, pre-scaled), K/V -> kall/vall fp32
    gemm_kernel<1><<<dim3(48, 32), 256, 0, stream>>>(xb, wqb, wkb, wvb,
                                                     qbf, kall, vall, nullptr);
    // K/V prep: history fp32 copy (replaces memcpys) + bf16 swizzled ktg/vtg
    prep_kv<<<dim3(64, 16, 2), 256, 0, stream>>>(pk, pv, kall, vall, ktg, vtg);
    // MFMA flash attention (1 barrier/tile, dbuf K+V, reg P-exchange)
    attn_mfma<<<dim3(32, 32), 256, 0, stream>>>(qbf, ktg, vtg, ot);
    // wo conversion (vtg now dead) + output projection -> out (fp32)
    cvt_kernel<<<512, 256, 0, stream>>>(wo, wob, 1048576);
    gemm_kernel<0><<<dim3(16, 32), 256, 0, stream>>>(ot, wob, wob, wob,
                                                     nullptr, nullptr, nullptr, out);
}